// Round 8
// baseline (145.388 us; speedup 1.0000x reference)
//
#include <hip/hip_runtime.h>
#include <math.h>

typedef _Float16 half8 __attribute__((ext_vector_type(8)));
typedef __fp16 fp16x2 __attribute__((ext_vector_type(2)));
typedef float floatx4 __attribute__((ext_vector_type(4)));

union U16 { uint4 u; half8 h; };

// ---------------------------------------------------------------------------
// prep: 133 blocks x 512 threads.
//  [0,64):    R rows d0=4*bid..+4 (f32), K=1024 split in halves, LDS reduce
//  [64,128):  a/bv rows r0=8*(bid-64) (f32); a += Whb
//  [128,132): WmPk fp8 granules (x16 scale): WmPk[k8*256+h] = fp8x8{Wm[k8*8..+8][h]*16}
//  [132]:     WoPk f16 granules: WoPk[k8*16+c] = f16x8{Wo[k8*8..+8][c]} (c<5 real)
// ---------------------------------------------------------------------------
__global__ __launch_bounds__(512) void k_prep(
    const float* __restrict__ hs, const float* __restrict__ Wh,
    const float* __restrict__ Whb, const float* __restrict__ Wo,
    float* __restrict__ R, float* __restrict__ a, float* __restrict__ bv,
    unsigned long long* __restrict__ WmPk, uint4* __restrict__ WoPk)
{
  __shared__ __align__(16) char pool[32768];
  int bid = blockIdx.x, tid = threadIdx.x;

  if (bid < 64) {                        // ---- R ----
    float (*tbl)[4] = (float(*)[4])pool;            // [1024 k][4 d] = 16 KB
    float* part = (float*)(pool + 16384);           // [4 d][256 h] = 4 KB
    int d0 = bid * 4;
    for (int idx = tid; idx < 4096; idx += 512) {
      int k = idx >> 2, dl = idx & 3;
      float e = (float)(k & ~1) * (1.0f / 1024.f);
      float div = powf(10000.f, e);
      float ang = (float)(d0 + dl) / div;
      tbl[k][dl] = (k & 1) ? cosf(ang) : sinf(ang);
    }
    __syncthreads();
    int h = tid & 255, s = tid >> 8;
    float acc[4] = {0.f, 0.f, 0.f, 0.f};
    for (int kk = 0; kk < 512; ++kk) {
      int k = s * 512 + kk;
      float wv = Wh[k * 256 + h];
      float4 tr = *(const float4*)&tbl[k][0];
      acc[0] = fmaf(tr.x, wv, acc[0]);
      acc[1] = fmaf(tr.y, wv, acc[1]);
      acc[2] = fmaf(tr.z, wv, acc[2]);
      acc[3] = fmaf(tr.w, wv, acc[3]);
    }
    if (s) {
#pragma unroll
      for (int dl = 0; dl < 4; ++dl) part[dl * 256 + h] = acc[dl];
    }
    __syncthreads();
    if (!s) {
#pragma unroll
      for (int dl = 0; dl < 4; ++dl)
        if (d0 + dl < 255)
          R[(d0 + dl) * 256 + h] = acc[dl] + part[dl * 256 + h];
    }

  } else if (bid < 128) {                // ---- a / bv (a includes Whb) ----
    float (*xs)[8] = (float(*)[8])pool;             // [256 k][8 r] = 8 KB
    float* pa = (float*)(pool + 8192);
    float* pb = (float*)(pool + 16384);
    int r0 = (bid - 64) * 8;
    for (int idx = tid; idx < 2048; idx += 512) {
      int k = idx & 255, r = idx >> 8;
      xs[k][r] = hs[(r0 + r) * 256 + k];
    }
    __syncthreads();
    int h = tid & 255, s = tid >> 8;
    float aa[8] = {0, 0, 0, 0, 0, 0, 0, 0}, bb[8] = {0, 0, 0, 0, 0, 0, 0, 0};
    for (int kk = 0; kk < 128; ++kk) {
      int k = s * 128 + kk;
      float we = Wh[k * 256 + h];
      float wsv = Wh[(256 + k) * 256 + h];
      float wd = Wh[(512 + k) * 256 + h];
      float wA = we + wd, wB = wsv - wd;
      float xr[8];
      *(float4*)&xr[0] = *(const float4*)&xs[k][0];
      *(float4*)&xr[4] = *(const float4*)&xs[k][4];
#pragma unroll
      for (int r = 0; r < 8; ++r) {
        aa[r] = fmaf(xr[r], wA, aa[r]);
        bb[r] = fmaf(xr[r], wB, bb[r]);
      }
    }
    if (s) {
#pragma unroll
      for (int r = 0; r < 8; ++r) { pa[r * 256 + h] = aa[r]; pb[r * 256 + h] = bb[r]; }
    }
    __syncthreads();
    if (!s) {
      float bias = Whb[h];
#pragma unroll
      for (int r = 0; r < 8; ++r) {
        a[(r0 + r) * 256 + h] = aa[r] + pa[r * 256 + h] + bias;
        bv[(r0 + r) * 256 + h] = bb[r] + pb[r * 256 + h];
      }
    }

  } else if (bid < 132) {                // ---- WmPk (fp8, x16) ----
    int q = bid - 128;
#pragma unroll
    for (int v = 0; v < 4; ++v) {
      int idx = v * 512 + tid;           // 0..2047
      int k8 = q * 8 + (idx >> 8);
      int h = idx & 255;
      const float* src = Wh + (768 + k8 * 8) * 256 + h;
      float f[8];
#pragma unroll
      for (int e = 0; e < 8; ++e) f[e] = src[e * 256] * 16.f;
      int lo = __builtin_amdgcn_cvt_pk_fp8_f32(f[0], f[1], 0, false);
      lo = __builtin_amdgcn_cvt_pk_fp8_f32(f[2], f[3], lo, true);
      int hi = __builtin_amdgcn_cvt_pk_fp8_f32(f[4], f[5], 0, false);
      hi = __builtin_amdgcn_cvt_pk_fp8_f32(f[6], f[7], hi, true);
      WmPk[k8 * 256 + h] =
          ((unsigned long long)(unsigned)hi << 32) | (unsigned)lo;
    }

  } else {                               // ---- WoPk (f16) ----
    int k8 = tid >> 4, c = tid & 15;     // 512 threads cover 32x16
    U16 v;
#pragma unroll
    for (int e = 0; e < 8; ++e)
      v.h[e] = (c < 5) ? (_Float16)Wo[(k8 * 8 + e) * 5 + c] : (_Float16)0.f;
    WoPk[tid] = v.u;
  }
}

// ---------------------------------------------------------------------------
// main: 512 blocks x 512 thr; block = (b, i), loops 8 j-tiles of 32.
// Wave w owns h' cols [32w,32w+32); its Wm slice lives in 32 VGPRs (loaded
// once) -> K-loop has NO global loads: 2 ds_read_b64 (fp8 A) + 4 MFMA /kstep.
// cv = a_i + bv_j + R_d loaded pre-barrier, consumed post-K-loop.
// Epilogue: tanh -> f16 P (separate LDS) -> waves 0,1 MFMA vs LDS Wo.
// ---------------------------------------------------------------------------
__global__ __launch_bounds__(512, 4) void k_main(
    const float* __restrict__ hs, const int* __restrict__ mask,
    const float* __restrict__ R, const float* __restrict__ a,
    const float* __restrict__ bvec,
    const unsigned long long* __restrict__ WmPk,
    const uint4* __restrict__ WoPk, const float* __restrict__ Wob,
    float* __restrict__ out)
{
  __shared__ __align__(16) unsigned char As[32][272];  // fp8 A-tile, 8.5 KB
  __shared__ __align__(16) __fp16 Ps[32][272];         // f16 P, 17 KB
  __shared__ __align__(16) uint4 WoL[512];             // Wo frags, 8 KB

  int bid = blockIdx.x, tid = threadIdx.x;
  int b = bid >> 8, i = bid & 255;
  int lane = tid & 63, w = tid >> 6;
  int c16 = lane & 15, quad = lane >> 4;
  const float* hsb = hs + (size_t)b * 65536;

  WoL[tid] = WoPk[tid];

  // ---- B-operand (Wm fp8 granules) into registers, once ----
  long long bg[8][2];
#pragma unroll
  for (int ks = 0; ks < 8; ++ks)
#pragma unroll
    for (int ct = 0; ct < 2; ++ct)
      bg[ks][ct] =
          (long long)WmPk[(ks * 4 + quad) * 256 + 32 * w + 16 * ct + c16];

  float av[2];
#pragma unroll
  for (int ct = 0; ct < 2; ++ct)
    av[ct] = a[((size_t)(b * 256 + i)) * 256 + 32 * w + 16 * ct + c16];

  const int* mb = mask + b * 256;
  int mi = mb[i];
  float wob = (c16 < 5) ? Wob[c16] : 0.f;

  int arow = tid >> 4;             // A-build: row 0..31
  int kg = (tid & 15) * 16;        // 16-k chunk
  const float* xip = hsb + i * 256 + kg;

#pragma unroll 1
  for (int jt = 0; jt < 8; ++jt) {
    int j0 = jt * 32;

    // ---- A-build: As[j][k] = fp8(x_i[k]*x_j[k]), one b128/thread ----
    {
      const float* xjp = hsb + (j0 + arow) * 256 + kg;
      float4 xi0 = *(const float4*)(xip);
      float4 xi1 = *(const float4*)(xip + 4);
      float4 xi2 = *(const float4*)(xip + 8);
      float4 xi3 = *(const float4*)(xip + 12);
      float4 xj0 = *(const float4*)(xjp);
      float4 xj1 = *(const float4*)(xjp + 4);
      float4 xj2 = *(const float4*)(xjp + 8);
      float4 xj3 = *(const float4*)(xjp + 12);
      int w0 = __builtin_amdgcn_cvt_pk_fp8_f32(xi0.x * xj0.x, xi0.y * xj0.y, 0, false);
      w0 = __builtin_amdgcn_cvt_pk_fp8_f32(xi0.z * xj0.z, xi0.w * xj0.w, w0, true);
      int w1 = __builtin_amdgcn_cvt_pk_fp8_f32(xi1.x * xj1.x, xi1.y * xj1.y, 0, false);
      w1 = __builtin_amdgcn_cvt_pk_fp8_f32(xi1.z * xj1.z, xi1.w * xj1.w, w1, true);
      int w2 = __builtin_amdgcn_cvt_pk_fp8_f32(xi2.x * xj2.x, xi2.y * xj2.y, 0, false);
      w2 = __builtin_amdgcn_cvt_pk_fp8_f32(xi2.z * xj2.z, xi2.w * xj2.w, w2, true);
      int w3 = __builtin_amdgcn_cvt_pk_fp8_f32(xi3.x * xj3.x, xi3.y * xj3.y, 0, false);
      w3 = __builtin_amdgcn_cvt_pk_fp8_f32(xi3.z * xj3.z, xi3.w * xj3.w, w3, true);
      uint4 pk = {(unsigned)w0, (unsigned)w1, (unsigned)w2, (unsigned)w3};
      *(uint4*)(&As[arow][kg]) = pk;
    }

    // ---- cv = a_i + bv_j + R_d: issued now, consumed after K-loop ----
    float cv[2][2][4];
#pragma unroll
    for (int rt = 0; rt < 2; ++rt)
#pragma unroll
      for (int r = 0; r < 4; ++r) {
        int jg = j0 + rt * 16 + quad * 4 + r;
        int dd = jg - i;
        dd = dd < -127 ? -127 : (dd > 127 ? 127 : dd);
        dd += 127;
        const float* bp = bvec + ((size_t)(b * 256 + jg)) * 256 + 32 * w + c16;
        const float* rp = R + dd * 256 + 32 * w + c16;
#pragma unroll
        for (int ct = 0; ct < 2; ++ct)
          cv[rt][ct][r] = av[ct] + bp[16 * ct] + rp[16 * ct];
      }
    __syncthreads();  // (1) As ready; prev-iter epilogue done

    // ---- K-loop: register B, LDS A, no loads ----
    floatx4 acc[2][2];
#pragma unroll
    for (int rt = 0; rt < 2; ++rt)
#pragma unroll
      for (int ct = 0; ct < 2; ++ct)
        acc[rt][ct] = (floatx4){0.f, 0.f, 0.f, 0.f};
#pragma unroll
    for (int ks = 0; ks < 8; ++ks) {
      long long a0 = *(const long long*)(&As[c16][ks * 32 + quad * 8]);
      long long a1 = *(const long long*)(&As[16 + c16][ks * 32 + quad * 8]);
      acc[0][0] = __builtin_amdgcn_mfma_f32_16x16x32_fp8_fp8(a0, bg[ks][0], acc[0][0], 0, 0, 0);
      acc[0][1] = __builtin_amdgcn_mfma_f32_16x16x32_fp8_fp8(a0, bg[ks][1], acc[0][1], 0, 0, 0);
      acc[1][0] = __builtin_amdgcn_mfma_f32_16x16x32_fp8_fp8(a1, bg[ks][0], acc[1][0], 0, 0, 0);
      acc[1][1] = __builtin_amdgcn_mfma_f32_16x16x32_fp8_fp8(a1, bg[ks][1], acc[1][1], 0, 0, 0);
    }

    // ---- tanh(acc/16 + cv) -> f16 P ----
#pragma unroll
    for (int rt = 0; rt < 2; ++rt)
#pragma unroll
      for (int ct = 0; ct < 2; ++ct) {
        int col = 32 * w + 16 * ct + c16;
#pragma unroll
        for (int r = 0; r < 4; r += 2) {
          int row = rt * 16 + quad * 4 + r;
          float p0 = fmaf(acc[rt][ct][r], 0.0625f, cv[rt][ct][r]);
          float p1 = fmaf(acc[rt][ct][r + 1], 0.0625f, cv[rt][ct][r + 1]);
          float t0 = 1.f - 2.f * __builtin_amdgcn_rcpf(__expf(2.f * p0) + 1.f);
          float t1 = 1.f - 2.f * __builtin_amdgcn_rcpf(__expf(2.f * p1) + 1.f);
          fp16x2 pk = __builtin_amdgcn_cvt_pkrtz(t0, t1);
          Ps[row][col] = pk.x;
          Ps[row + 1][col] = pk.y;
        }
      }
    __syncthreads();  // (2) P ready; all A-reads done (next A-build safe)

    // ---- epilogue (waves 0,1): 16 rows x 16c, K=256, f16 MFMA ----
    if (w < 2) {
      floatx4 accE = {0.f, 0.f, 0.f, 0.f};
#pragma unroll
      for (int ks = 0; ks < 8; ++ks) {
        half8 pa = *(const half8*)(&Ps[w * 16 + c16][ks * 32 + quad * 8]);
        U16 wv;
        wv.u = WoL[(ks * 4 + quad) * 16 + c16];
        accE = __builtin_amdgcn_mfma_f32_16x16x32_f16(pa, wv.h, accE, 0, 0, 0);
      }
#pragma unroll
      for (int r = 0; r < 4; ++r) {
        int jg = j0 + w * 16 + quad * 4 + r;
        float v = accE[r] + wob;
        if (!(mi && mb[jg])) v = -__builtin_inff();
        if (jg < i) v -= 1e12f;
        if (c16 < 5) out[(((size_t)b * 5 + c16) * 256 + i) * 256 + jg] = v;
      }
    }
  }
}

extern "C" void kernel_launch(void* const* d_in, const int* in_sizes, int n_in,
                              void* d_out, int out_size, void* d_ws, size_t ws_size,
                              hipStream_t stream) {
  const float* hs   = (const float*)d_in[0];
  const int*   mask = (const int*)d_in[1];
  const float* Wh_w = (const float*)d_in[2];
  const float* Wh_b = (const float*)d_in[3];
  const float* Wo_w = (const float*)d_in[4];
  const float* Wo_b = (const float*)d_in[5];

  char* ws = (char*)d_ws;
  float* R    = (float*)(ws + 0);                        // 255*256*4 (pad 256K)
  float* a    = (float*)(ws + 262144);                   // 512*256*4
  float* bv   = (float*)(ws + 786432);                   // 512*256*4
  unsigned long long* WmPk = (unsigned long long*)(ws + 1310720);  // 32*256*8 = 64K
  uint4* WoPk = (uint4*)(ws + 1376256);                  // 512*16 = 8K

  k_prep<<<133, 512, 0, stream>>>(hs, Wh_w, Wh_b, Wo_w, R, a, bv, WmPk, WoPk);
  k_main<<<512, 512, 0, stream>>>(hs, mask, R, a, bv, WmPk, WoPk, Wo_b,
                                  (float*)d_out);
}